// Round 3
// baseline (2201.033 us; speedup 1.0000x reference)
//
#include <hip/hip_runtime.h>
#include <math.h>
#include <climits>

#define SQ 4096          // sequence length
#define HD 1024          // hidden
#define PD 4096          // pool size
#define DD 512           // pool dim
#define MR 16384         // B*S rows
#define INTERD 1024
#define SP 4104          // padded sequence rows per batch (4 + 4096 + 4)
#define NCAND 6          // rescored candidates per row

typedef __attribute__((ext_vector_type(8))) short short8;
typedef __attribute__((ext_vector_type(4))) float f32x4;

__device__ __forceinline__ unsigned short f2bf(float f) {
    union { float f; unsigned u; } v; v.f = f;
    unsigned r = v.u + 0x7fff + ((v.u >> 16) & 1);
    return (unsigned short)(r >> 16);
}

__device__ __forceinline__ void gll16(const unsigned short* g, unsigned short* l) {
    __builtin_amdgcn_global_load_lds(
        (const __attribute__((address_space(1))) void*)g,
        (__attribute__((address_space(3))) void*)l, 16, 0, 0);
}

// fast tanh-GELU (max dev from erf-GELU ~3e-4; outputs stored bf16 anyway)
__device__ __forceinline__ float gelu_f(float v) {
    float u = v * (0.7978845608028654f + 0.03567740813636141f * v * v);
    float e = __expf(2.0f * u);
    float th = 1.0f - 2.0f / (e + 1.0f);
    return 0.5f * v * (1.0f + th);
}

// ===========================================================================
// bf16 MFMA GEMM body: 128x128 tile, BK=64, 256 threads (4 waves), 16x16x32.
// C[m,n] = EPI( sum_k A[m,k]*B[n,k] + bias[n] )
// AMODE 0: A bf16 row-major [M, lda]
// AMODE 1: A = xpad gather: m->(b,s), k->(tap,cin); row b*SP + s+4+(tap-1)*dil
// AMODE 2: A split across 3 row-major [M,1024] buffers by tap: A, Ax1, Ax2
// BMODE 0: B bf16 row-major [N, ldb]
// BMODE 1: B = wconvb gather: [tap][n][cin] (base pre-offset for conv i)
// EPI 0: Cf = acc+bias (fp32) | 1: bf16(gelu) | 2: bf16 | 3: gate-combine
// EPI 4: per-row top-2 per 64-col wave-group -> cand_v/cand_i [row][128]
// ===========================================================================
template<int AMODE, int BMODE, int EPI>
__device__ __forceinline__
void bgemm_body(unsigned short* As, unsigned short* Bs, int bx, int by,
                const unsigned short* __restrict__ A, int lda,
                const unsigned short* __restrict__ Bm, int ldb,
                const float* __restrict__ bias,
                float* __restrict__ Cf, unsigned short* __restrict__ Cb,
                int ldc, int coff, int K, int dil,
                const float* __restrict__ gate,
                float* __restrict__ cand_v, int* __restrict__ cand_i,
                const unsigned short* __restrict__ Ax1,
                const unsigned short* __restrict__ Ax2)
{
    const int tid = threadIdx.x;
    const int w = tid >> 6;          // wave 0..3
    const int ln = tid & 63;
    const int bm = by * 128;
    const int bn = bx * 128;
    const int wm = (w >> 1) * 64;    // wave m-offset
    const int wn = (w & 1) * 64;     // wave n-offset

    f32x4 acc[4][4] = {};

    const int l8 = (ln & 7) * 8;         // elem offset within 64-wide k-tile
    const int rsub = w * 8 + (ln >> 3);  // staged row for q=0

    for (int kt = 0; kt < K; kt += 64) {
        const int tap = kt >> 10;
        const int cin0 = kt & 1023;
#pragma unroll
        for (int q = 0; q < 4; ++q) {
            const int r = q * 32 + rsub;
            const unsigned short* asrc;
            if (AMODE == 0) {
                asrc = A + (size_t)(bm + r) * lda + kt + l8;
            } else if (AMODE == 1) {
                int m = bm + r;
                int b = m >> 12;
                int s = m & (SQ - 1);
                asrc = A + (size_t)(b * SP + s + 4 + (tap - 1) * dil) * 1024 + cin0 + l8;
            } else {
                const unsigned short* ab = (tap == 0) ? A : (tap == 1) ? Ax1 : Ax2;
                asrc = ab + (size_t)(bm + r) * 1024 + cin0 + l8;
            }
            gll16(asrc, &As[q * 2048 + w * 512]);
            const unsigned short* bsrc;
            if (BMODE == 0) {
                bsrc = Bm + (size_t)(bn + r) * ldb + kt + l8;
            } else {
                bsrc = Bm + (size_t)(tap * 1024 + bn + r) * 1024 + cin0 + l8;
            }
            gll16(bsrc, &Bs[q * 2048 + w * 512]);
        }
        __syncthreads();
#pragma unroll
        for (int ks = 0; ks < 2; ++ks) {
            const int kb = ks * 32 + (ln >> 4) * 8;
            short8 af[4], bf[4];
#pragma unroll
            for (int i = 0; i < 4; ++i)
                af[i] = *(const short8*)&As[(wm + i * 16 + (ln & 15)) * 64 + kb];
#pragma unroll
            for (int j = 0; j < 4; ++j)
                bf[j] = *(const short8*)&Bs[(wn + j * 16 + (ln & 15)) * 64 + kb];
#pragma unroll
            for (int i = 0; i < 4; ++i)
#pragma unroll
                for (int j = 0; j < 4; ++j)
                    acc[i][j] = __builtin_amdgcn_mfma_f32_16x16x32_bf16(
                        af[i], bf[j], acc[i][j], 0, 0, 0);
        }
        __syncthreads();
    }

    if constexpr (EPI == 4) {
        // top-2 per row within this wave's 64 cols, ranked (v desc, idx asc)
        const int g = bx * 2 + (w & 1);   // col-group 0..63
#pragma unroll
        for (int i = 0; i < 4; ++i) {
#pragma unroll
            for (int r = 0; r < 4; ++r) {
                float v0 = -1e30f, v1 = -1e30f; int i0 = INT_MAX, i1 = INT_MAX;
#pragma unroll
                for (int j = 0; j < 4; ++j) {
                    const int col = bn + wn + j * 16 + (ln & 15);
                    float v = acc[i][j][r] + bias[col];
                    if (v > v0 || (v == v0 && col < i0)) { v1 = v0; i1 = i0; v0 = v; i0 = col; }
                    else if (v > v1 || (v == v1 && col < i1)) { v1 = v; i1 = col; }
                }
#pragma unroll
                for (int msk = 1; msk <= 8; msk <<= 1) {
                    float ov0 = __shfl_xor(v0, msk); int oi0 = __shfl_xor(i0, msk);
                    float ov1 = __shfl_xor(v1, msk); int oi1 = __shfl_xor(i1, msk);
                    if (ov0 > v0 || (ov0 == v0 && oi0 < i0)) {
                        if (v0 > ov1 || (v0 == ov1 && i0 < oi1)) { v1 = v0; i1 = i0; }
                        else { v1 = ov1; i1 = oi1; }
                        v0 = ov0; i0 = oi0;
                    } else {
                        if (ov0 > v1 || (ov0 == v1 && oi0 < i1)) { v1 = ov0; i1 = oi0; }
                    }
                }
                if ((ln & 15) == 0) {
                    const int row = bm + wm + i * 16 + (ln >> 4) * 4 + r;
                    size_t base = (size_t)row * 128 + g * 2;
                    cand_v[base] = v0; cand_v[base + 1] = v1;
                    cand_i[base] = i0; cand_i[base + 1] = i1;
                }
            }
        }
        return;
    }

    // epilogue: D row = (ln>>4)*4 + r, col = ln&15 within each 16x16 tile
#pragma unroll
    for (int i = 0; i < 4; ++i) {
        const int mrow = bm + wm + i * 16 + (ln >> 4) * 4;
#pragma unroll
        for (int j = 0; j < 4; ++j) {
            const int ncol = bn + wn + j * 16 + (ln & 15);
            const float bs = bias[ncol];
#pragma unroll
            for (int r = 0; r < 4; ++r) {
                const int m = mrow + r;
                float v = acc[i][j][r] + bs;
                if (EPI == 0) {
                    Cf[(size_t)m * ldc + coff + ncol] = v;
                } else if (EPI == 1) {
                    Cb[(size_t)m * ldc + coff + ncol] = f2bf(gelu_f(v));
                } else if (EPI == 2) {
                    Cb[(size_t)m * ldc + coff + ncol] = f2bf(v);
                } else if (EPI == 3) {
                    float g = gate[m];
                    size_t o = (size_t)m * 1024 + ncol;
                    Cf[o] = g * v + (1.0f - g) * Cf[o];
                }
            }
        }
    }
}

template<int AMODE, int BMODE, int EPI>
__global__ __launch_bounds__(256)
void bgemm_k(const unsigned short* __restrict__ A, int lda,
             const unsigned short* __restrict__ Bm, int ldb,
             const float* __restrict__ bias,
             float* __restrict__ Cf, unsigned short* __restrict__ Cb,
             int ldc, int coff, int K, int dil,
             const float* __restrict__ gate,
             float* __restrict__ cand_v, int* __restrict__ cand_i,
             const unsigned short* __restrict__ Ax1,
             const unsigned short* __restrict__ Ax2)
{
    __shared__ __align__(16) unsigned short As[128 * 64];
    __shared__ __align__(16) unsigned short Bs[128 * 64];
    bgemm_body<AMODE, BMODE, EPI>(As, Bs, blockIdx.x, blockIdx.y,
        A, lda, Bm, ldb, bias, Cf, Cb, ldc, coff, K, dil, gate,
        cand_v, cand_i, Ax1, Ax2);
}

// ===========================================================================
// fp32 G1 body: inter = relu(x @ w1^T + b1), dual-write fp32 + bf16.
// 128x128 tile, BK=16, 256 threads, 8x8/thread. (v1 structure, 72 VGPR;
// the R1 BK=32+reg-dbuf rewrite spilled; the R2 K-rotation was neutral-to-
// negative -> reverted. G1's residual ~34% idle is barrier-bound; we hide it
// by co-scheduling with MFMA conv blocks in fusedg1conv_k below, m114-style.)
// ===========================================================================
__device__ __forceinline__
void g1_body(float* As, float* Bs, int bx, int by,
             const float* __restrict__ A, const float* __restrict__ Bm,
             const float* __restrict__ bias,
             float* __restrict__ C, unsigned short* __restrict__ Cb)
{
    const int tid = threadIdx.x;
    const int tx = tid & 15;
    const int ty = tid >> 4;
    const int bm = by * 128;
    const int bn = bx * 128;

    float acc[8][8] = {};

    for (int kt = 0; kt < HD; kt += 16) {
#pragma unroll
        for (int l = 0; l < 2; ++l) {
            int idx = tid + l * 256;          // 0..511
            int m = idx >> 2;                 // 0..127
            int c4 = (idx & 3) * 4;           // 0,4,8,12
            float4 va = *(const float4*)&A[(size_t)(bm + m) * HD + kt + c4];
            As[(c4 + 0) * 132 + m] = va.x;
            As[(c4 + 1) * 132 + m] = va.y;
            As[(c4 + 2) * 132 + m] = va.z;
            As[(c4 + 3) * 132 + m] = va.w;
            float4 vb = *(const float4*)&Bm[(size_t)(bn + m) * HD + kt + c4];
            Bs[(c4 + 0) * 132 + m] = vb.x;
            Bs[(c4 + 1) * 132 + m] = vb.y;
            Bs[(c4 + 2) * 132 + m] = vb.z;
            Bs[(c4 + 3) * 132 + m] = vb.w;
        }
        __syncthreads();
#pragma unroll
        for (int c = 0; c < 16; ++c) {
            float4 a0 = *(const float4*)&As[c * 132 + ty * 8];
            float4 a1 = *(const float4*)&As[c * 132 + ty * 8 + 4];
            float4 b0 = *(const float4*)&Bs[c * 132 + tx * 8];
            float4 b1 = *(const float4*)&Bs[c * 132 + tx * 8 + 4];
            float a[8] = {a0.x, a0.y, a0.z, a0.w, a1.x, a1.y, a1.z, a1.w};
            float b[8] = {b0.x, b0.y, b0.z, b0.w, b1.x, b1.y, b1.z, b1.w};
#pragma unroll
            for (int i = 0; i < 8; ++i)
#pragma unroll
                for (int j = 0; j < 8; ++j)
                    acc[i][j] = fmaf(a[i], b[j], acc[i][j]);
        }
        __syncthreads();
    }

    float bs[8];
#pragma unroll
    for (int j = 0; j < 8; ++j) bs[j] = bias[bn + tx * 8 + j];
#pragma unroll
    for (int i = 0; i < 8; ++i) {
        const int m = bm + ty * 8 + i;
        float v[8];
#pragma unroll
        for (int j = 0; j < 8; ++j) v[j] = fmaxf(acc[i][j] + bs[j], 0.f);
        float* cp = C + (size_t)m * INTERD + bn + tx * 8;
        *(float4*)cp = make_float4(v[0], v[1], v[2], v[3]);
        *(float4*)(cp + 4) = make_float4(v[4], v[5], v[6], v[7]);
        unsigned u[4];
#pragma unroll
        for (int j = 0; j < 4; ++j)
            u[j] = (unsigned)f2bf(v[2 * j]) | ((unsigned)f2bf(v[2 * j + 1]) << 16);
        *(uint4*)(Cb + (size_t)m * INTERD + bn + tx * 8) =
            make_uint4(u[0], u[1], u[2], u[3]);
    }
}

// ===========================================================================
// fused: G1 (fp32 VALU GEMM) co-scheduled with conv dil=1 and dil=2 (bf16
// MFMA GEMMs). Independent dataflow; different pipes (m114: VALU-wave and
// MFMA-wave on one CU run at ~max, not sum). block type = blockIdx.x % 3.
// ===========================================================================
__global__ __launch_bounds__(256)
void fusedg1conv_k(const float* __restrict__ x, const float* __restrict__ w1,
                   const float* __restrict__ b1,
                   float* __restrict__ inter, unsigned short* __restrict__ inter_b,
                   const unsigned short* __restrict__ xpad,
                   const unsigned short* __restrict__ wconvb,
                   const float* __restrict__ convb,
                   unsigned short* __restrict__ c0out,
                   unsigned short* __restrict__ c1out)
{
    __shared__ __align__(16) char smem[32768];   // union: G1 16.9KB | conv 32KB
    const int bt = blockIdx.x % 3;
    const int tile = blockIdx.x / 3;             // 0..1023
    const int bx = tile & 7;
    const int by = tile >> 3;
    if (bt == 0) {
        g1_body((float*)smem, (float*)(smem + 8448), bx, by, x, w1, b1, inter, inter_b);
    } else {
        unsigned short* As = (unsigned short*)smem;
        unsigned short* Bs = (unsigned short*)(smem + 16384);
        const int i = bt - 1;                    // conv 0 (dil=1) / conv 1 (dil=2)
        bgemm_body<1, 1, 1>(As, Bs, bx, by,
            xpad, 0, wconvb + (size_t)i * 3145728, 0,
            convb + i * HD, nullptr, (i == 0 ? c0out : c1out),
            1024, 0, 3072, (i == 0 ? 1 : 2),
            nullptr, nullptr, nullptr, nullptr, nullptr);
    }
}

// ===========================================================================
// rescore: wave-0 shuffle top-6 of 128 candidates -> all-thread fp32 dots ->
// reference-exact top-2 / softmax / usage / weighted_map (bf16 out).
// ===========================================================================
__global__ __launch_bounds__(128)
void rescore_k(const float* __restrict__ cand_v, const int* __restrict__ cand_i,
               const float* __restrict__ inter, const float* __restrict__ w2,
               const float* __restrict__ b2, const float* __restrict__ tptr,
               const float* __restrict__ pool,
               unsigned short* __restrict__ combined_b, float* __restrict__ usage)
{
    const int row = blockIdx.x;
    const int t = threadIdx.x;
    const int lane = t & 63;
    const int wv = t >> 6;
    __shared__ int   ssel[NCAND];
    __shared__ float pw[2][NCAND];
    __shared__ float wsh[2];
    __shared__ int   ish[2];

    // every thread: its 8 inter values (k = t + 128*q)
    float xr[8];
    const float* irow = inter + (size_t)row * INTERD;
#pragma unroll
    for (int q = 0; q < 8; ++q) xr[q] = irow[t + q * 128];

    // wave 0: top-NCAND selection from the 128 bf16 candidates
    if (wv == 0) {
        float v0 = cand_v[(size_t)row * 128 + lane];
        float v1 = cand_v[(size_t)row * 128 + 64 + lane];
        int   i0 = cand_i[(size_t)row * 128 + lane];
        int   i1 = cand_i[(size_t)row * 128 + 64 + lane];
        if (v1 > v0 || (v1 == v0 && i1 < i0)) {
            float tv = v0; v0 = v1; v1 = tv;
            int ti = i0; i0 = i1; i1 = ti;
        }
        for (int j = 0; j < NCAND; ++j) {
            float bv = v0; int bi = i0;
#pragma unroll
            for (int m = 32; m >= 1; m >>= 1) {
                float ov = __shfl_xor(bv, m);
                int oi = __shfl_xor(bi, m);
                if (ov > bv || (ov == bv && oi < bi)) { bv = ov; bi = oi; }
            }
            if (lane == 0) ssel[j] = bi;
            if (i0 == bi) { v0 = v1; i0 = i1; v1 = -1e30f; i1 = INT_MAX; }
        }
    }
    __syncthreads();

    int sel[NCAND];
#pragma unroll
    for (int j = 0; j < NCAND; ++j) sel[j] = ssel[j];
    float p[NCAND];
#pragma unroll
    for (int j = 0; j < NCAND; ++j) {
        const float* wr = w2 + (size_t)sel[j] * INTERD + t;
        float pj = 0.f;
#pragma unroll
        for (int q = 0; q < 8; ++q) pj = fmaf(xr[q], wr[q * 128], pj);
        p[j] = pj;
    }
#pragma unroll
    for (int j = 0; j < NCAND; ++j) {
#pragma unroll
        for (int m = 32; m >= 1; m >>= 1) p[j] += __shfl_xor(p[j], m);
    }
    if (lane == 0) {
#pragma unroll
        for (int j = 0; j < NCAND; ++j) pw[wv][j] = p[j];
    }
    __syncthreads();

    if (t == 0) {
        float tc = fminf(fmaxf(tptr[0], 0.1f), 5.0f);
        float bv0 = -1e30f, bv1 = -1e30f; int bi0 = INT_MAX, bi1 = INT_MAX;
        for (int j = 0; j < NCAND; ++j) {
            float logit = pw[0][j] + pw[1][j] + b2[sel[j]];
            float v = fminf(fmaxf(logit / tc, -10.f), 10.f);
            int n = sel[j];
            if (v > bv0 || (v == bv0 && n < bi0)) { bv1 = bv0; bi1 = bi0; bv0 = v; bi0 = n; }
            else if (v > bv1 || (v == bv1 && n < bi1)) { bv1 = v; bi1 = n; }
        }
        float e1 = expf(bv1 - bv0);
        float w0 = 1.f / (1.f + e1);
        float w1 = e1 / (1.f + e1);
        atomicAdd(&usage[bi0], w0);
        atomicAdd(&usage[bi1], w1);
        wsh[0] = w0; wsh[1] = w1; ish[0] = bi0; ish[1] = bi1;
    }
    __syncthreads();
    float w0 = wsh[0], w1 = wsh[1];
    const float* p0 = pool + (size_t)ish[0] * DD;
    const float* p1 = pool + (size_t)ish[1] * DD;
    unsigned short* dst = combined_b + (size_t)row * 1024 + 512;
#pragma unroll
    for (int q = 0; q < 4; ++q) {
        int j = t + q * 128;
        dst[j] = f2bf(w0 * p0[j] + w1 * p1[j]);
    }
}

// layernorm projx fp32 -> combined_b[:, :512] bf16
__global__ __launch_bounds__(256)
void ln_k(const float* __restrict__ projx, unsigned short* __restrict__ combined_b,
          const float* __restrict__ g, const float* __restrict__ b)
{
    int row = blockIdx.x;
    int t = threadIdx.x;
    const float* p = projx + (size_t)row * DD;
    float x0 = p[t], x1 = p[t + 256];
    __shared__ float s1[256], s2[256];
    s1[t] = x0 + x1;
    s2[t] = x0 * x0 + x1 * x1;
    __syncthreads();
    for (int o = 128; o > 0; o >>= 1) {
        if (t < o) { s1[t] += s1[t + o]; s2[t] += s2[t + o]; }
        __syncthreads();
    }
    float mu = s1[0] * (1.0f / 512.0f);
    float var = s2[0] * (1.0f / 512.0f) - mu * mu;
    float inv = rsqrtf(var + 1e-5f);
    unsigned short* dst = combined_b + (size_t)row * 1024;
    dst[t]       = f2bf((x0 - mu) * inv * g[t] + b[t]);
    dst[t + 256] = f2bf((x1 - mu) * inv * g[t + 256] + b[t + 256]);
}

__global__ __launch_bounds__(256)
void gate_k(const float* __restrict__ x, const float* __restrict__ wg,
            const float* __restrict__ bg, float* __restrict__ gate)
{
    int row = blockIdx.x;
    int t = threadIdx.x;
    const float* p = x + (size_t)row * HD;
    float s = p[t] * wg[t] + p[t + 256] * wg[t + 256]
            + p[t + 512] * wg[t + 512] + p[t + 768] * wg[t + 768];
    __shared__ float s1[256];
    s1[t] = s;
    __syncthreads();
    for (int o = 128; o > 0; o >>= 1) {
        if (t < o) s1[t] += s1[t + o];
        __syncthreads();
    }
    if (t == 0) gate[row] = 1.f / (1.f + expf(-(s1[0] + bg[0])));
}

__global__ __launch_bounds__(1024)
void divloss_k(const float* __restrict__ usage, float* __restrict__ out)
{
    int t = threadIdx.x;
    float u[4];
#pragma unroll
    for (int q = 0; q < 4; ++q) u[q] = usage[t + q * 1024];
    __shared__ float s1[1024];
    s1[t] = u[0] + u[1] + u[2] + u[3];
    __syncthreads();
    for (int o = 512; o > 0; o >>= 1) {
        if (t < o) s1[t] += s1[t + o];
        __syncthreads();
    }
    float inv = 1.0f / (s1[0] + 1e-8f);
    __syncthreads();
    float acc = 0.f;
#pragma unroll
    for (int q = 0; q < 4; ++q) {
        float d = u[q] * inv - (1.0f / 4096.0f);
        acc += d * d;
    }
    s1[t] = acc;
    __syncthreads();
    for (int o = 512; o > 0; o >>= 1) {
        if (t < o) s1[t] += s1[t + o];
        __syncthreads();
    }
    if (t == 0) out[(size_t)MR * HD] = s1[0] * (1.0f / 4096.0f) * 0.01f;
}

// ---- conversion kernels ----
__global__ __launch_bounds__(256)
void xpad_k(const float* __restrict__ x, unsigned short* __restrict__ xpad)
{
    size_t idx = (size_t)blockIdx.x * 256 + threadIdx.x;  // over 4*SP*1024
    int c = (int)(idx & 1023);
    int sp = (int)((idx >> 10) % SP);
    int b = (int)(idx / ((size_t)SP * 1024));
    float v = 0.f;
    if (sp >= 4 && sp < SQ + 4)
        v = x[((size_t)b * SQ + sp - 4) * 1024 + c];
    xpad[idx] = f2bf(v);
}

// conv_w [i][o][in][3] -> wconvb [i][tap][o][in]
__global__ __launch_bounds__(256)
void wconv_k(const float* __restrict__ cw, unsigned short* __restrict__ wb)
{
    size_t idx = (size_t)blockIdx.x * 256 + threadIdx.x;  // over 9*1024*1024
    int it = (int)(idx >> 20);       // i*3+tap
    int i = it / 3, tap = it % 3;
    int o = (int)((idx >> 10) & 1023);
    int in = (int)(idx & 1023);
    wb[idx] = f2bf(cw[(((size_t)(i * 1024 + o)) * 1024 + in) * 3 + tap]);
}

__global__ __launch_bounds__(256)
void cvt_k(const float* __restrict__ src, unsigned short* __restrict__ dst, int n)
{
    int idx = blockIdx.x * 256 + threadIdx.x;
    if (idx < n) dst[idx] = f2bf(src[idx]);
}

extern "C" void kernel_launch(void* const* d_in, const int* in_sizes, int n_in,
                              void* d_out, int out_size, void* d_ws, size_t ws_size,
                              hipStream_t stream)
{
    const float* x     = (const float*)d_in[0];
    const float* pool  = (const float*)d_in[1];
    const float* w1    = (const float*)d_in[2];
    const float* b1    = (const float*)d_in[3];
    const float* w2    = (const float*)d_in[4];
    const float* b2    = (const float*)d_in[5];
    const float* temp  = (const float*)d_in[6];
    const float* wproj = (const float*)d_in[7];
    const float* bproj = (const float*)d_in[8];
    const float* ln_g  = (const float*)d_in[9];
    const float* ln_b  = (const float*)d_in[10];
    const float* wmap  = (const float*)d_in[11];
    const float* bmap  = (const float*)d_in[12];
    const float* convw = (const float*)d_in[13];
    const float* convb = (const float*)d_in[14];
    const float* wout  = (const float*)d_in[15];
    const float* bout  = (const float*)d_in[16];
    const float* wrp   = (const float*)d_in[17];
    const float* brp   = (const float*)d_in[18];
    const float* wg    = (const float*)d_in[19];
    const float* bg    = (const float*)d_in[20];
    float* out = (float*)d_out;

    // ---- workspace map v4 (fused schedule). Peak 245,514,240 B.
    // A [0, 67108864): inter fp32 (fused..rescore);
    //   then conv2out [0, 33554432) + projx [33554432, 67108864)
    // B [67108864, 100663296): inter_b (fused..G2cand); then combined_b
    // C [100663296, 134217728): conv0out (fused..wout)
    // D [134217728, 167772160): conv1out (fused..wout)
    // E [167772160, 201392128): xpad (..wproj)
    // F [201392128, 220266496): wconvb (..conv2); then wprojb/wmapb/wrpb
    // G [220266496, 228655104): w2b (..G2cand); then woutb
    // H [228655104, 245432320): cand_v+cand_i (G2cand..rescore); then trans_b
    // I [245432320, 245514240): gate, usage
    char* w8 = (char*)d_ws;
    float*          inter      = (float*)(w8 + 0);
    unsigned short* conv2out   = (unsigned short*)(w8 + 0);
    float*          projx      = (float*)(w8 + 33554432);
    unsigned short* inter_b    = (unsigned short*)(w8 + 67108864);
    unsigned short* combined_b = (unsigned short*)(w8 + 67108864);
    unsigned short* conv0out   = (unsigned short*)(w8 + 100663296);
    unsigned short* conv1out   = (unsigned short*)(w8 + 134217728);
    unsigned short* xpad       = (unsigned short*)(w8 + 167772160);
    unsigned short* wconvb     = (unsigned short*)(w8 + 201392128);
    unsigned short* wprojb     = (unsigned short*)(w8 + 201392128);  // after conv2
    unsigned short* wmapb      = (unsigned short*)(w8 + 201392128);  // after wproj
    unsigned short* wrpb       = (unsigned short*)(w8 + 202440704);
    unsigned short* w2b        = (unsigned short*)(w8 + 220266496);
    unsigned short* woutb      = (unsigned short*)(w8 + 220266496);  // after G2cand
    float*          cand_v     = (float*)(w8 + 228655104);
    int*            cand_i     = (int*)(w8 + 237043712);
    unsigned short* trans_b    = (unsigned short*)(w8 + 228655104);  // after rescore
    float*          gate       = (float*)(w8 + 245432320);
    float*          usage      = (float*)(w8 + 245497856);

    hipMemsetAsync(usage, 0, PD * sizeof(float), stream);

    dim3 blk(256);
    // --- P1: conversions needed by the fused phase ---
    xpad_k<<<dim3((4 * SP * 1024) / 256), blk, 0, stream>>>(x, xpad);
    wconv_k<<<dim3((9 * 1024 * 1024) / 256), blk, 0, stream>>>(convw, wconvb);
    cvt_k<<<dim3((PD * INTERD + 255) / 256), blk, 0, stream>>>(w2, w2b, PD * INTERD);

    // --- P2: FUSED G1 (VALU) + conv dil=1,2 (MFMA), 3072 blocks interleaved
    fusedg1conv_k<<<dim3(3072), blk, 0, stream>>>(
        x, w1, b1, inter, inter_b, xpad, wconvb, convb, conv0out, conv1out);

    // --- P4: G2cand bf16 MFMA logits, top-2 per 64-col group ---
    bgemm_k<0, 0, 4><<<dim3(32, 128), blk, 0, stream>>>(inter_b, INTERD, w2b, INTERD,
        b2, nullptr, nullptr, 0, 0, INTERD, 0, nullptr, cand_v, cand_i,
        nullptr, nullptr);
    // --- P5: exact fp32 rescore + selection + weighted_map + usage ---
    rescore_k<<<dim3(MR), dim3(128), 0, stream>>>(cand_v, cand_i, inter, w2, b2,
        temp, pool, combined_b, usage);

    // --- P6: conv dil=4 into freed inter region ---
    bgemm_k<1, 1, 1><<<dim3(8, 128), blk, 0, stream>>>(
        xpad, 0, wconvb + (size_t)2 * 3145728, 0, convb + 2 * HD,
        nullptr, conv2out, 1024, 0, 3072, 4, nullptr, nullptr, nullptr,
        nullptr, nullptr);

    // --- global branch ---
    cvt_k<<<dim3((512 * 1024 + 255) / 256), blk, 0, stream>>>(wproj, wprojb, 512 * 1024);
    bgemm_k<1, 0, 0><<<dim3(4, 128), blk, 0, stream>>>(xpad, 0, wprojb, HD, bproj,
        projx, nullptr, DD, 0, HD, 0, nullptr, nullptr, nullptr, nullptr, nullptr);
    ln_k<<<dim3(MR), dim3(256), 0, stream>>>(projx, combined_b, ln_g, ln_b);
    cvt_k<<<dim3((512 * 1024 + 255) / 256), blk, 0, stream>>>(wmap, wmapb, 512 * 1024);
    cvt_k<<<dim3((1024 * 512 + 255) / 256), blk, 0, stream>>>(wrp, wrpb, 1024 * 512);
    bgemm_k<0, 0, 2><<<dim3(4, 128), blk, 0, stream>>>(combined_b, 1024, wmapb, 1024,
        bmap, nullptr, trans_b, DD, 0, 1024, 0, nullptr, nullptr, nullptr,
        nullptr, nullptr);
    bgemm_k<0, 0, 0><<<dim3(8, 128), blk, 0, stream>>>(trans_b, DD, wrpb, DD, brp,
        out, nullptr, HD, 0, DD, 0, nullptr, nullptr, nullptr, nullptr, nullptr);
    gate_k<<<dim3(MR), dim3(256), 0, stream>>>(x, wg, bg, gate);
    divloss_k<<<dim3(1), dim3(1024), 0, stream>>>(usage, out);

    // --- wout GEMM with fused gate-combine: out = g*local + (1-g)*out ---
    cvt_k<<<dim3((1024 * 3072 + 255) / 256), blk, 0, stream>>>(wout, woutb, 1024 * 3072);
    bgemm_k<2, 0, 3><<<dim3(8, 128), blk, 0, stream>>>(conv0out, 1024, woutb, 3072,
        bout, out, nullptr, HD, 0, 3072, 0, gate, nullptr, nullptr,
        conv1out, conv2out);
}

// Round 4
// 1673.518 us; speedup vs baseline: 1.3152x; 1.3152x over previous
//
#include <hip/hip_runtime.h>
#include <math.h>
#include <climits>

#define SQ 4096          // sequence length
#define HD 1024          // hidden
#define PD 4096          // pool size
#define DD 512           // pool dim
#define MR 16384         // B*S rows
#define INTERD 1024
#define SP 4104          // padded sequence rows per batch (4 + 4096 + 4)
#define NCAND 6          // rescored candidates per row

typedef __attribute__((ext_vector_type(8))) short short8;
typedef __attribute__((ext_vector_type(4))) float f32x4;

__device__ __forceinline__ unsigned short f2bf(float f) {
    union { float f; unsigned u; } v; v.f = f;
    unsigned r = v.u + 0x7fff + ((v.u >> 16) & 1);
    return (unsigned short)(r >> 16);
}

__device__ __forceinline__ float bf2f(unsigned short h) {
    union { unsigned u; float f; } v; v.u = ((unsigned)h) << 16;
    return v.f;
}

__device__ __forceinline__ void gll16(const unsigned short* g, unsigned short* l) {
    __builtin_amdgcn_global_load_lds(
        (const __attribute__((address_space(1))) void*)g,
        (__attribute__((address_space(3))) void*)l, 16, 0, 0);
}

// fast tanh-GELU (max dev from erf-GELU ~3e-4; outputs stored bf16 anyway)
__device__ __forceinline__ float gelu_f(float v) {
    float u = v * (0.7978845608028654f + 0.03567740813636141f * v * v);
    float e = __expf(2.0f * u);
    float th = 1.0f - 2.0f / (e + 1.0f);
    return 0.5f * v * (1.0f + th);
}

// ===========================================================================
// bf16 MFMA GEMM: 128x128 tile, BK=64, 256 threads (4 waves), 16x16x32 mfma.
// C[m,n] = EPI( sum_k A[m,k]*B[n,k] + bias[n] )
// AMODE 0: A bf16 row-major [M, lda]
// AMODE 1: A = xpad gather: m->(b,s), k->(tap,cin); row b*SP + s+4+(tap-1)*dil
// AMODE 3: split-bf16: K=4096, quarter q=kt>>10 -> (q&1 ? Ax : A)[m][k&1023]
// BMODE 0: B bf16 row-major [N, ldb]
// BMODE 1: B = wconvb gather: [tap][n][cin] (base pre-offset for conv i)
// BMODE 2: split-bf16: quarter q -> (q>>1 ? Bx : Bm)[n][k&1023]
// EPI 0: Cf = acc+bias (fp32) | 1: bf16(gelu) | 2: bf16 | 3: gate-combine
// EPI 4: per-row top-2 per 64-col wave-group -> cand_v/cand_i [row][128]
// EPI 5: relu dual-write: Cf fp32 + Cb bf16 (split-bf16 G1 replacement)
// ===========================================================================
template<int AMODE, int BMODE, int EPI>
__global__ __launch_bounds__(256)
void bgemm_k(const unsigned short* __restrict__ A, int lda,
             const unsigned short* __restrict__ Bm, int ldb,
             const float* __restrict__ bias,
             float* __restrict__ Cf, unsigned short* __restrict__ Cb,
             int ldc, int coff, int K, int dil,
             const float* __restrict__ gate,
             float* __restrict__ cand_v, int* __restrict__ cand_i,
             const unsigned short* __restrict__ Ax,
             const unsigned short* __restrict__ Bx)
{
    __shared__ __align__(16) unsigned short As[128 * 64];
    __shared__ __align__(16) unsigned short Bs[128 * 64];
    const int tid = threadIdx.x;
    const int w = tid >> 6;          // wave 0..3
    const int ln = tid & 63;
    const int bm = blockIdx.y * 128;
    const int bn = blockIdx.x * 128;
    const int wm = (w >> 1) * 64;    // wave m-offset
    const int wn = (w & 1) * 64;     // wave n-offset

    f32x4 acc[4][4] = {};

    const int l8 = (ln & 7) * 8;         // elem offset within 64-wide k-tile
    const int rsub = w * 8 + (ln >> 3);  // staged row for q=0

    for (int kt = 0; kt < K; kt += 64) {
        const int tap = kt >> 10;        // also the split-quarter index
        const int cin0 = kt & 1023;
#pragma unroll
        for (int q = 0; q < 4; ++q) {
            const int r = q * 32 + rsub;
            const unsigned short* asrc;
            if (AMODE == 0) {
                asrc = A + (size_t)(bm + r) * lda + kt + l8;
            } else if (AMODE == 1) {
                int m = bm + r;
                int b = m >> 12;
                int s = m & (SQ - 1);
                asrc = A + (size_t)(b * SP + s + 4 + (tap - 1) * dil) * 1024 + cin0 + l8;
            } else {  // AMODE 3: quarters [hi, lo, hi, lo]
                const unsigned short* ab = (tap & 1) ? Ax : A;
                asrc = ab + (size_t)(bm + r) * 1024 + cin0 + l8;
            }
            gll16(asrc, &As[q * 2048 + w * 512]);
            const unsigned short* bsrc;
            if (BMODE == 0) {
                bsrc = Bm + (size_t)(bn + r) * ldb + kt + l8;
            } else if (BMODE == 1) {
                bsrc = Bm + (size_t)(tap * 1024 + bn + r) * 1024 + cin0 + l8;
            } else {  // BMODE 2: quarters [hi, hi, lo, lo]
                const unsigned short* bb = (tap >> 1) ? Bx : Bm;
                bsrc = bb + (size_t)(bn + r) * 1024 + cin0 + l8;
            }
            gll16(bsrc, &Bs[q * 2048 + w * 512]);
        }
        __syncthreads();
#pragma unroll
        for (int ks = 0; ks < 2; ++ks) {
            const int kb = ks * 32 + (ln >> 4) * 8;
            short8 af[4], bf[4];
#pragma unroll
            for (int i = 0; i < 4; ++i)
                af[i] = *(const short8*)&As[(wm + i * 16 + (ln & 15)) * 64 + kb];
#pragma unroll
            for (int j = 0; j < 4; ++j)
                bf[j] = *(const short8*)&Bs[(wn + j * 16 + (ln & 15)) * 64 + kb];
#pragma unroll
            for (int i = 0; i < 4; ++i)
#pragma unroll
                for (int j = 0; j < 4; ++j)
                    acc[i][j] = __builtin_amdgcn_mfma_f32_16x16x32_bf16(
                        af[i], bf[j], acc[i][j], 0, 0, 0);
        }
        __syncthreads();
    }

    if constexpr (EPI == 4) {
        // top-2 per row within this wave's 64 cols, ranked (v desc, idx asc)
        const int g = blockIdx.x * 2 + (w & 1);   // col-group 0..63
#pragma unroll
        for (int i = 0; i < 4; ++i) {
#pragma unroll
            for (int r = 0; r < 4; ++r) {
                float v0 = -1e30f, v1 = -1e30f; int i0 = INT_MAX, i1 = INT_MAX;
#pragma unroll
                for (int j = 0; j < 4; ++j) {
                    const int col = bn + wn + j * 16 + (ln & 15);
                    float v = acc[i][j][r] + bias[col];
                    if (v > v0 || (v == v0 && col < i0)) { v1 = v0; i1 = i0; v0 = v; i0 = col; }
                    else if (v > v1 || (v == v1 && col < i1)) { v1 = v; i1 = col; }
                }
#pragma unroll
                for (int msk = 1; msk <= 8; msk <<= 1) {
                    float ov0 = __shfl_xor(v0, msk); int oi0 = __shfl_xor(i0, msk);
                    float ov1 = __shfl_xor(v1, msk); int oi1 = __shfl_xor(i1, msk);
                    if (ov0 > v0 || (ov0 == v0 && oi0 < i0)) {
                        if (v0 > ov1 || (v0 == ov1 && i0 < oi1)) { v1 = v0; i1 = i0; }
                        else { v1 = ov1; i1 = oi1; }
                        v0 = ov0; i0 = oi0;
                    } else {
                        if (ov0 > v1 || (ov0 == v1 && oi0 < i1)) { v1 = ov0; i1 = oi0; }
                    }
                }
                if ((ln & 15) == 0) {
                    const int row = bm + wm + i * 16 + (ln >> 4) * 4 + r;
                    size_t base = (size_t)row * 128 + g * 2;
                    cand_v[base] = v0; cand_v[base + 1] = v1;
                    cand_i[base] = i0; cand_i[base + 1] = i1;
                }
            }
        }
        return;
    }

    // epilogue: D row = (ln>>4)*4 + r, col = ln&15 within each 16x16 tile
#pragma unroll
    for (int i = 0; i < 4; ++i) {
        const int mrow = bm + wm + i * 16 + (ln >> 4) * 4;
#pragma unroll
        for (int j = 0; j < 4; ++j) {
            const int ncol = bn + wn + j * 16 + (ln & 15);
            const float bs = bias[ncol];
#pragma unroll
            for (int r = 0; r < 4; ++r) {
                const int m = mrow + r;
                float v = acc[i][j][r] + bs;
                if (EPI == 0) {
                    Cf[(size_t)m * ldc + coff + ncol] = v;
                } else if (EPI == 1) {
                    Cb[(size_t)m * ldc + coff + ncol] = f2bf(gelu_f(v));
                } else if (EPI == 2) {
                    Cb[(size_t)m * ldc + coff + ncol] = f2bf(v);
                } else if (EPI == 3) {
                    float g = gate[m];
                    size_t o = (size_t)m * 1024 + ncol;
                    Cf[o] = g * v + (1.0f - g) * Cf[o];
                } else if (EPI == 5) {
                    float rv = fmaxf(v, 0.f);
                    Cf[(size_t)m * ldc + coff + ncol] = rv;
                    Cb[(size_t)m * ldc + coff + ncol] = f2bf(rv);
                }
            }
        }
    }
}

// ===========================================================================
// split fp32 -> (hi, lo) bf16 pair: hi = bf16(v), lo = bf16(v - hi).
// Residual <= 2^-18 |v|; a K=4096 bf16 MFMA GEMM over quarters
// A:[hi,lo,hi,lo] x B:[hi,hi,lo,lo] reproduces the fp32 product to ~4e-6 rel.
// ===========================================================================
__global__ __launch_bounds__(256)
void split_k(const float* __restrict__ src, unsigned short* __restrict__ hi,
             unsigned short* __restrict__ lo, int n4)
{
    int i = blockIdx.x * 256 + threadIdx.x;
    if (i >= n4) return;
    float4 v = ((const float4*)src)[i];
    ushort4 h, l;
    h.x = f2bf(v.x); l.x = f2bf(v.x - bf2f(h.x));
    h.y = f2bf(v.y); l.y = f2bf(v.y - bf2f(h.y));
    h.z = f2bf(v.z); l.z = f2bf(v.z - bf2f(h.z));
    h.w = f2bf(v.w); l.w = f2bf(v.w - bf2f(h.w));
    ((ushort4*)hi)[i] = h;
    ((ushort4*)lo)[i] = l;
}

// ===========================================================================
// rescore: wave-0 shuffle top-6 of 128 candidates -> all-thread fp32 dots ->
// reference-exact top-2 / softmax / usage / weighted_map (bf16 out).
// ===========================================================================
__global__ __launch_bounds__(128)
void rescore_k(const float* __restrict__ cand_v, const int* __restrict__ cand_i,
               const float* __restrict__ inter, const float* __restrict__ w2,
               const float* __restrict__ b2, const float* __restrict__ tptr,
               const float* __restrict__ pool,
               unsigned short* __restrict__ combined_b, float* __restrict__ usage)
{
    const int row = blockIdx.x;
    const int t = threadIdx.x;
    const int lane = t & 63;
    const int wv = t >> 6;
    __shared__ int   ssel[NCAND];
    __shared__ float pw[2][NCAND];
    __shared__ float wsh[2];
    __shared__ int   ish[2];

    // every thread: its 8 inter values (k = t + 128*q)
    float xr[8];
    const float* irow = inter + (size_t)row * INTERD;
#pragma unroll
    for (int q = 0; q < 8; ++q) xr[q] = irow[t + q * 128];

    // wave 0: top-NCAND selection from the 128 bf16 candidates
    if (wv == 0) {
        float v0 = cand_v[(size_t)row * 128 + lane];
        float v1 = cand_v[(size_t)row * 128 + 64 + lane];
        int   i0 = cand_i[(size_t)row * 128 + lane];
        int   i1 = cand_i[(size_t)row * 128 + 64 + lane];
        if (v1 > v0 || (v1 == v0 && i1 < i0)) {
            float tv = v0; v0 = v1; v1 = tv;
            int ti = i0; i0 = i1; i1 = ti;
        }
        for (int j = 0; j < NCAND; ++j) {
            float bv = v0; int bi = i0;
#pragma unroll
            for (int m = 32; m >= 1; m >>= 1) {
                float ov = __shfl_xor(bv, m);
                int oi = __shfl_xor(bi, m);
                if (ov > bv || (ov == bv && oi < bi)) { bv = ov; bi = oi; }
            }
            if (lane == 0) ssel[j] = bi;
            if (i0 == bi) { v0 = v1; i0 = i1; v1 = -1e30f; i1 = INT_MAX; }
        }
    }
    __syncthreads();

    int sel[NCAND];
#pragma unroll
    for (int j = 0; j < NCAND; ++j) sel[j] = ssel[j];
    float p[NCAND];
#pragma unroll
    for (int j = 0; j < NCAND; ++j) {
        const float* wr = w2 + (size_t)sel[j] * INTERD + t;
        float pj = 0.f;
#pragma unroll
        for (int q = 0; q < 8; ++q) pj = fmaf(xr[q], wr[q * 128], pj);
        p[j] = pj;
    }
#pragma unroll
    for (int j = 0; j < NCAND; ++j) {
#pragma unroll
        for (int m = 32; m >= 1; m >>= 1) p[j] += __shfl_xor(p[j], m);
    }
    if (lane == 0) {
#pragma unroll
        for (int j = 0; j < NCAND; ++j) pw[wv][j] = p[j];
    }
    __syncthreads();

    if (t == 0) {
        float tc = fminf(fmaxf(tptr[0], 0.1f), 5.0f);
        float bv0 = -1e30f, bv1 = -1e30f; int bi0 = INT_MAX, bi1 = INT_MAX;
        for (int j = 0; j < NCAND; ++j) {
            float logit = pw[0][j] + pw[1][j] + b2[sel[j]];
            float v = fminf(fmaxf(logit / tc, -10.f), 10.f);
            int n = sel[j];
            if (v > bv0 || (v == bv0 && n < bi0)) { bv1 = bv0; bi1 = bi0; bv0 = v; bi0 = n; }
            else if (v > bv1 || (v == bv1 && n < bi1)) { bv1 = v; bi1 = n; }
        }
        float e1 = expf(bv1 - bv0);
        float w0 = 1.f / (1.f + e1);
        float w1 = e1 / (1.f + e1);
        atomicAdd(&usage[bi0], w0);
        atomicAdd(&usage[bi1], w1);
        wsh[0] = w0; wsh[1] = w1; ish[0] = bi0; ish[1] = bi1;
    }
    __syncthreads();
    float w0 = wsh[0], w1 = wsh[1];
    const float* p0 = pool + (size_t)ish[0] * DD;
    const float* p1 = pool + (size_t)ish[1] * DD;
    unsigned short* dst = combined_b + (size_t)row * 1024 + 512;
#pragma unroll
    for (int q = 0; q < 4; ++q) {
        int j = t + q * 128;
        dst[j] = f2bf(w0 * p0[j] + w1 * p1[j]);
    }
}

// layernorm projx fp32 -> combined_b[:, :512] bf16
__global__ __launch_bounds__(256)
void ln_k(const float* __restrict__ projx, unsigned short* __restrict__ combined_b,
          const float* __restrict__ g, const float* __restrict__ b)
{
    int row = blockIdx.x;
    int t = threadIdx.x;
    const float* p = projx + (size_t)row * DD;
    float x0 = p[t], x1 = p[t + 256];
    __shared__ float s1[256], s2[256];
    s1[t] = x0 + x1;
    s2[t] = x0 * x0 + x1 * x1;
    __syncthreads();
    for (int o = 128; o > 0; o >>= 1) {
        if (t < o) { s1[t] += s1[t + o]; s2[t] += s2[t + o]; }
        __syncthreads();
    }
    float mu = s1[0] * (1.0f / 512.0f);
    float var = s2[0] * (1.0f / 512.0f) - mu * mu;
    float inv = rsqrtf(var + 1e-5f);
    unsigned short* dst = combined_b + (size_t)row * 1024;
    dst[t]       = f2bf((x0 - mu) * inv * g[t] + b[t]);
    dst[t + 256] = f2bf((x1 - mu) * inv * g[t + 256] + b[t + 256]);
}

__global__ __launch_bounds__(256)
void gate_k(const float* __restrict__ x, const float* __restrict__ wg,
            const float* __restrict__ bg, float* __restrict__ gate)
{
    int row = blockIdx.x;
    int t = threadIdx.x;
    const float* p = x + (size_t)row * HD;
    float s = p[t] * wg[t] + p[t + 256] * wg[t + 256]
            + p[t + 512] * wg[t + 512] + p[t + 768] * wg[t + 768];
    __shared__ float s1[256];
    s1[t] = s;
    __syncthreads();
    for (int o = 128; o > 0; o >>= 1) {
        if (t < o) s1[t] += s1[t + o];
        __syncthreads();
    }
    if (t == 0) gate[row] = 1.f / (1.f + expf(-(s1[0] + bg[0])));
}

__global__ __launch_bounds__(1024)
void divloss_k(const float* __restrict__ usage, float* __restrict__ out)
{
    int t = threadIdx.x;
    float u[4];
#pragma unroll
    for (int q = 0; q < 4; ++q) u[q] = usage[t + q * 1024];
    __shared__ float s1[1024];
    s1[t] = u[0] + u[1] + u[2] + u[3];
    __syncthreads();
    for (int o = 512; o > 0; o >>= 1) {
        if (t < o) s1[t] += s1[t + o];
        __syncthreads();
    }
    float inv = 1.0f / (s1[0] + 1e-8f);
    __syncthreads();
    float acc = 0.f;
#pragma unroll
    for (int q = 0; q < 4; ++q) {
        float d = u[q] * inv - (1.0f / 4096.0f);
        acc += d * d;
    }
    s1[t] = acc;
    __syncthreads();
    for (int o = 512; o > 0; o >>= 1) {
        if (t < o) s1[t] += s1[t + o];
        __syncthreads();
    }
    if (t == 0) out[(size_t)MR * HD] = s1[0] * (1.0f / 4096.0f) * 0.01f;
}

// ---- conversion kernels ----
__global__ __launch_bounds__(256)
void xpad_k(const float* __restrict__ x, unsigned short* __restrict__ xpad)
{
    size_t idx = (size_t)blockIdx.x * 256 + threadIdx.x;  // over 4*SP*1024
    int c = (int)(idx & 1023);
    int sp = (int)((idx >> 10) % SP);
    int b = (int)(idx / ((size_t)SP * 1024));
    float v = 0.f;
    if (sp >= 4 && sp < SQ + 4)
        v = x[((size_t)b * SQ + sp - 4) * 1024 + c];
    xpad[idx] = f2bf(v);
}

// conv_w [i][o][in][3] -> wconvb [i][tap][o][in]
__global__ __launch_bounds__(256)
void wconv_k(const float* __restrict__ cw, unsigned short* __restrict__ wb)
{
    size_t idx = (size_t)blockIdx.x * 256 + threadIdx.x;  // over 9*1024*1024
    int it = (int)(idx >> 20);       // i*3+tap
    int i = it / 3, tap = it % 3;
    int o = (int)((idx >> 10) & 1023);
    int in = (int)(idx & 1023);
    wb[idx] = f2bf(cw[(((size_t)(i * 1024 + o)) * 1024 + in) * 3 + tap]);
}

__global__ __launch_bounds__(256)
void cvt_k(const float* __restrict__ src, unsigned short* __restrict__ dst, int n)
{
    int idx = blockIdx.x * 256 + threadIdx.x;
    if (idx < n) dst[idx] = f2bf(src[idx]);
}

extern "C" void kernel_launch(void* const* d_in, const int* in_sizes, int n_in,
                              void* d_out, int out_size, void* d_ws, size_t ws_size,
                              hipStream_t stream)
{
    const float* x     = (const float*)d_in[0];
    const float* pool  = (const float*)d_in[1];
    const float* w1    = (const float*)d_in[2];
    const float* b1    = (const float*)d_in[3];
    const float* w2    = (const float*)d_in[4];
    const float* b2    = (const float*)d_in[5];
    const float* temp  = (const float*)d_in[6];
    const float* wproj = (const float*)d_in[7];
    const float* bproj = (const float*)d_in[8];
    const float* ln_g  = (const float*)d_in[9];
    const float* ln_b  = (const float*)d_in[10];
    const float* wmap  = (const float*)d_in[11];
    const float* bmap  = (const float*)d_in[12];
    const float* convw = (const float*)d_in[13];
    const float* convb = (const float*)d_in[14];
    const float* wout  = (const float*)d_in[15];
    const float* bout  = (const float*)d_in[16];
    const float* wrp   = (const float*)d_in[17];
    const float* brp   = (const float*)d_in[18];
    const float* wg    = (const float*)d_in[19];
    const float* bg    = (const float*)d_in[20];
    float* out = (float*)d_out;

    char* w8 = (char*)d_ws;
    float*          inter      = (float*)(w8 + 0);                  // 67.1 MB fp32 [until rescore]
    unsigned short* inter_b    = (unsigned short*)(w8 + 67108864);  // 33.6 MB bf16 [until G2cand done]
    unsigned short* concat     = (unsigned short*)(w8 + 0);         // 100.7 MB, aliases inter+inter_b (conv phase)
    float*          projx      = (float*)(w8 + 100663296);          // 33.6 MB
    unsigned short* combined_b = (unsigned short*)(w8 + 134217728); // 33.6 MB
    unsigned short* trans_b    = (unsigned short*)(w8 + 167772160); // 16.8 MB
    float*          cand_v     = (float*)(w8 + 184549376);          // 8.4 MB  [until rescore]
    int*            cand_i     = (int*)(w8 + 192937984);            // 8.4 MB  [until rescore]
    unsigned short* xpad       = (unsigned short*)(w8 + 184549376); // 33.6 MB, aliases cand (after rescore)
    unsigned short* wconvb     = (unsigned short*)(w8 + 218169344); // 18.9 MB
    unsigned short* woutb      = (unsigned short*)(w8 + 237043712); // 6.3 MB
    unsigned short* w2b        = (unsigned short*)(w8 + 237043712); // 8.4 MB, aliases wout/wmap/wrp slots (early)
    unsigned short* wmapb      = (unsigned short*)(w8 + 243335168); // 1.0 MB
    unsigned short* wrpb       = (unsigned short*)(w8 + 244383744); // 1.0 MB
    unsigned short* wprojb     = (unsigned short*)(w8 + 245432320); // 1.0 MB
    float*          gate       = (float*)(w8 + 246480896);          // 64 KB
    float*          usage      = (float*)(w8 + 246546432);          // 16 KB
    // split-bf16 G1 operands, live ONLY during the first GEMM:
    unsigned short* xhi        = (unsigned short*)(w8 + 100663296); // 33.6 MB, aliases projx (dead until wproj)
    unsigned short* xlo        = (unsigned short*)(w8 + 134217728); // 33.6 MB, aliases combined_b (dead until rescore)
    unsigned short* w1hi       = (unsigned short*)(w8 + 167772160); // 2.1 MB, aliases trans_b (dead until wmap)
    unsigned short* w1lo       = (unsigned short*)(w8 + 169869312); // 2.1 MB

    hipMemsetAsync(usage, 0, PD * sizeof(float), stream);

    dim3 blk(256);
    // --- router ---
    // G1 split-bf16: inter = relu(x@w1^T+b1) via K=4096 bf16 MFMA over
    // quarters A:[hi,lo,hi,lo] x B:[hi,hi,lo,lo]; fp32 + bf16 dual write.
    split_k<<<dim3((MR * HD / 4 + 255) / 256), blk, 0, stream>>>(x, xhi, xlo, MR * HD / 4);
    split_k<<<dim3((INTERD * HD / 4 + 255) / 256), blk, 0, stream>>>(w1, w1hi, w1lo, INTERD * HD / 4);
    bgemm_k<3, 2, 5><<<dim3(8, 128), blk, 0, stream>>>(xhi, 1024, w1hi, 1024,
        b1, inter, inter_b, INTERD, 0, 4096, 0, nullptr, nullptr, nullptr,
        xlo, w1lo);
    // w2 -> bf16 (region reused by wout/wmap/wrp later)
    cvt_k<<<dim3((PD * INTERD + 255) / 256), blk, 0, stream>>>(w2, w2b, PD * INTERD);
    // G2cand: bf16 MFMA logits, top-2 per 64-col group
    bgemm_k<0, 0, 4><<<dim3(32, 128), blk, 0, stream>>>(inter_b, INTERD, w2b, INTERD,
        b2, nullptr, nullptr, 0, 0, INTERD, 0, nullptr, cand_v, cand_i,
        nullptr, nullptr);
    // exact fp32 rescore + selection + weighted_map + usage
    rescore_k<<<dim3(MR), dim3(128), 0, stream>>>(cand_v, cand_i, inter, w2, b2,
        temp, pool, combined_b, usage);

    // --- conversions (cand + inter regions dead; aliases safe) ---
    xpad_k<<<dim3((4 * SP * 1024) / 256), blk, 0, stream>>>(x, xpad);
    wconv_k<<<dim3((9 * 1024 * 1024) / 256), blk, 0, stream>>>(convw, wconvb);
    cvt_k<<<dim3((1024 * 3072 + 255) / 256), blk, 0, stream>>>(wout, woutb, 1024 * 3072);
    cvt_k<<<dim3((512 * 1024 + 255) / 256), blk, 0, stream>>>(wmap, wmapb, 512 * 1024);
    cvt_k<<<dim3((1024 * 512 + 255) / 256), blk, 0, stream>>>(wrp, wrpb, 1024 * 512);
    cvt_k<<<dim3((512 * 1024 + 255) / 256), blk, 0, stream>>>(wproj, wprojb, 512 * 1024);

    // --- global branch (bf16 MFMA) ---
    bgemm_k<1, 0, 0><<<dim3(4, 128), blk, 0, stream>>>(xpad, 0, wprojb, HD, bproj,
        projx, nullptr, DD, 0, HD, 0, nullptr, nullptr, nullptr, nullptr, nullptr);
    ln_k<<<dim3(MR), dim3(256), 0, stream>>>(projx, combined_b, ln_g, ln_b);
    bgemm_k<0, 0, 2><<<dim3(4, 128), blk, 0, stream>>>(combined_b, 1024, wmapb, 1024,
        bmap, nullptr, trans_b, DD, 0, 1024, 0, nullptr, nullptr, nullptr,
        nullptr, nullptr);
    bgemm_k<0, 0, 0><<<dim3(8, 128), blk, 0, stream>>>(trans_b, DD, wrpb, DD, brp,
        out, nullptr, HD, 0, DD, 0, nullptr, nullptr, nullptr, nullptr, nullptr);
    gate_k<<<dim3(MR), dim3(256), 0, stream>>>(x, wg, bg, gate);
    divloss_k<<<dim3(1), dim3(1024), 0, stream>>>(usage, out);

    // --- local branch (bf16 MFMA) ---
    const int dils[3] = {1, 2, 4};
    for (int i = 0; i < 3; ++i) {
        bgemm_k<1, 1, 1><<<dim3(8, 128), blk, 0, stream>>>(
            xpad, 0, wconvb + (size_t)i * 3 * 1024 * 1024, 0,
            convb + (size_t)i * HD,
            nullptr, concat, 3072, i * 1024, 3072, dils[i], nullptr, nullptr,
            nullptr, nullptr, nullptr);
    }
    // wout GEMM with fused gate-combine: out = g*local + (1-g)*out
    bgemm_k<0, 0, 3><<<dim3(8, 128), blk, 0, stream>>>(concat, 3072, woutb, 3072,
        bout, out, nullptr, HD, 0, 3072, 0, gate, nullptr, nullptr,
        nullptr, nullptr);
}